// Round 3
// baseline (982.489 us; speedup 1.0000x reference)
//
#include <hip/hip_runtime.h>
#include <math.h>

#define NB 256      // B
#define NK 1024     // K
#define ND 2048     // D
#define NN 50000    // N
#define BMW 32      // rows per (single-wave) block
#define NT 32       // K-tiles of 64 floats

constexpr float T_INV = 1.0f / 0.07f;
constexpr float Z_INV = 1.0f / 52580.0f;
constexpr float MOM   = 0.5f;

typedef float f32x4 __attribute__((ext_vector_type(4)));
typedef short s16x8 __attribute__((ext_vector_type(8)));
typedef unsigned int u32x4 __attribute__((ext_vector_type(4)));

#define AS1 __attribute__((address_space(1)))
#define AS3 __attribute__((address_space(3)))
#define SB() __builtin_amdgcn_sched_barrier(0)

// ---------------------------------------------------------------- helpers
__device__ __forceinline__ float blk_reduce_sum256(float v, float* sh) {
    #pragma unroll
    for (int o = 32; o > 0; o >>= 1) v += __shfl_down(v, o, 64);
    int lane = threadIdx.x & 63;
    int wid  = threadIdx.x >> 6;
    if (lane == 0) sh[wid] = v;
    __syncthreads();
    float s = sh[0] + sh[1] + sh[2] + sh[3];
    __syncthreads();
    return s;
}

__device__ __forceinline__ unsigned f2bf_rne(float f) {
    unsigned u = __float_as_uint(f);
    return (u + 0x7fffu + ((u >> 16) & 1u)) >> 16;
}

// truncating fp32->bf16 pack of 8 floats (same numerics as prior passing rounds)
__device__ __forceinline__ s16x8 pack_bf16(f32x4 a, f32x4 b) {
    u32x4 uv = { (__float_as_uint(a[0]) >> 16) | (__float_as_uint(a[1]) & 0xffff0000u),
                 (__float_as_uint(a[2]) >> 16) | (__float_as_uint(a[3]) & 0xffff0000u),
                 (__float_as_uint(b[0]) >> 16) | (__float_as_uint(b[1]) & 0xffff0000u),
                 (__float_as_uint(b[2]) >> 16) | (__float_as_uint(b[3]) & 0xffff0000u) };
    return __builtin_bit_cast(s16x8, uv);
}

// ------------------------------------------- 1) feat = x/||x||  (+ bf16 copy)
__global__ void k_feat(const float* __restrict__ x, float* __restrict__ feat,
                       unsigned int* __restrict__ featb) {   // featb: [NB][ND/2] bf16x2
    __shared__ float sh[4];
    int b = blockIdx.x;
    int t = threadIdx.x;
    const float4* xr = (const float4*)(x + (size_t)b * ND);
    float4 v0 = xr[t];
    float4 v1 = xr[t + 256];
    float ss = v0.x*v0.x + v0.y*v0.y + v0.z*v0.z + v0.w*v0.w
             + v1.x*v1.x + v1.y*v1.y + v1.z*v1.z + v1.w*v1.w;
    float s = blk_reduce_sum256(ss, sh);
    float r = rsqrtf(s);
    v0.x*=r; v0.y*=r; v0.z*=r; v0.w*=r;
    v1.x*=r; v1.y*=r; v1.z*=r; v1.w*=r;
    float4* fr = (float4*)(feat + (size_t)b * ND);
    fr[t]       = v0;
    fr[t + 256] = v1;
    unsigned int* fb = featb + (size_t)b * (ND / 2);
    fb[2*t]           = f2bf_rne(v0.x) | (f2bf_rne(v0.y) << 16);
    fb[2*t + 1]       = f2bf_rne(v0.z) | (f2bf_rne(v0.w) << 16);
    fb[2*(t+256)]     = f2bf_rne(v1.x) | (f2bf_rne(v1.y) << 16);
    fb[2*(t+256) + 1] = f2bf_rne(v1.z) | (f2bf_rne(v1.w) << 16);
}

// ------------- 2) S[n,b] = dot(mem[n], feat[b])  (+ fused temp copy from LDS)
// ONE wave per block, 32 rows x all 256 cols. No barriers: wave-private LDS
// double buffer, global_load_lds staging (XOR-swizzled source, linear dest),
// exact counted vmcnt (steady: st8 + B32 + gll8 = 48). B (featb) is L2-hot.
template<bool COPY>
__launch_bounds__(64, 2)
__global__ void k_gemm(const float* __restrict__ mem, const short* __restrict__ featb,
                       float* __restrict__ S, float* __restrict__ temp) {
    __shared__ __align__(16) float As[2][BMW * 64];   // 2 x 8 KB
    const int l   = threadIdx.x;       // 0..63
    const int rlo = l & 15;
    const int khi = l >> 4;            // 0..3
    const int n0  = blockIdx.x * BMW;

    // Staging geometry: gll instr q (q=0..7) covers rows 4q..4q+3; this lane
    // stages row rq = 4q+khi, phys chunk rlo. Source chunk = rlo ^ (rq&15)
    // (inverse swizzle) so frag reads at phys (c ^ rlo) are conflict-free.
    unsigned off[8];
    bool     cva[8];
    #pragma unroll
    for (int q = 0; q < 8; ++q) {
        int rq  = 4 * q + khi;
        int row = n0 + rq;
        cva[q]  = row < NN;
        int rc  = cva[q] ? row : (NN - 1);
        off[q]  = (unsigned)rc * ND + (unsigned)((rlo ^ (rq & 15)) * 4);
    }

    const short* bk0 = featb + (size_t)rlo * ND + khi * 8;  // B frag base (L2-hot)

    f32x4 acc[2][16] = {};

    auto GLL = [&](int buf, int kf) {
        #pragma unroll
        for (int q = 0; q < 8; ++q)
            __builtin_amdgcn_global_load_lds((const AS1 void*)(mem + (size_t)off[q] + kf),
                (AS3 void*)(&As[buf][q * 256]), 16, 0, 0);
    };

    auto BODY = [&](int i, int buf) {
        const float* ab = As[buf];
        const int kf = i * 64;
        if (COPY) {   // temp copy served from LDS (mem hits HBM exactly once)
            f32x4 cv[8];
            #pragma unroll
            for (int q = 0; q < 8; ++q) cv[q] = *(const f32x4*)(ab + q * 256 + l * 4);
            #pragma unroll
            for (int q = 0; q < 8; ++q)
                if (cva[q]) *(f32x4*)(temp + (size_t)off[q] + kf) = cv[q];
        }
        const short* bk = bk0 + kf;
        #pragma unroll
        for (int s = 0; s < 2; ++s) {
            const int cb = s * 8 + khi * 2;
            f32x4 a00 = *(const f32x4*)(ab + rlo * 64        + ((cb + 0) ^ rlo) * 4);
            f32x4 a01 = *(const f32x4*)(ab + rlo * 64        + ((cb + 1) ^ rlo) * 4);
            f32x4 a10 = *(const f32x4*)(ab + (16 + rlo) * 64 + ((cb + 0) ^ rlo) * 4);
            f32x4 a11 = *(const f32x4*)(ab + (16 + rlo) * 64 + ((cb + 1) ^ rlo) * 4);
            s16x8 af0 = pack_bf16(a00, a01);
            s16x8 af1 = pack_bf16(a10, a11);
            #pragma unroll
            for (int g = 0; g < 16; ++g) {
                s16x8 bf = *(const s16x8*)(bk + s * 32 + (size_t)g * (16 * ND));
                acc[0][g] = __builtin_amdgcn_mfma_f32_16x16x32_bf16(af0, bf, acc[0][g], 0, 0, 0);
                acc[1][g] = __builtin_amdgcn_mfma_f32_16x16x32_bf16(af1, bf, acc[1][g], 0, 0, 0);
            }
        }
    };

    constexpr int W_STEADY = COPY ? 48 : 40;   // st8 + B32 [+0] + gll8
    constexpr int W_LAST   = COPY ? 40 : 32;   // st8 + B32 (no trailing gll)

    // prologue: two tiles in flight before first compute
    GLL(0, 0);
    SB();
    GLL(1, 64);
    asm volatile("s_waitcnt vmcnt(8)" ::: "memory");   // gll(0) landed, gll(1) flying
    SB();
    BODY(0, 0);
    for (int i = 1; i < NT - 1; ++i) {
        SB();
        GLL((i + 1) & 1, (i + 1) * 64);
        asm volatile("s_waitcnt vmcnt(%0)" :: "n"(W_STEADY) : "memory");  // gll(i) landed
        SB();
        BODY(i, i & 1);
    }
    SB();
    asm volatile("s_waitcnt vmcnt(%0)" :: "n"(W_LAST) : "memory");        // gll(NT-1) landed
    SB();
    BODY(NT - 1, (NT - 1) & 1);

    // C-write: S[n0 + m*16 + khi*4 + r][g*16 + rlo] = acc[m][g][r]
    #pragma unroll
    for (int m = 0; m < 2; ++m) {
        #pragma unroll
        for (int r = 0; r < 4; ++r) {
            int row = n0 + m * 16 + khi * 4 + r;
            if (row < NN) {
                #pragma unroll
                for (int g = 0; g < 16; ++g)
                    S[(size_t)row * NB + g * 16 + rlo] = acc[m][g][r];
            }
        }
    }
}

// --------------------------- 3) out[b,k] = exp(S[row,b]/T)/Z, row = (k==0? y : idx)
__global__ void k_out(const float* __restrict__ S, const int* __restrict__ idx,
                      const int* __restrict__ y, float* __restrict__ out) {
    int g = blockIdx.x * 256 + threadIdx.x;
    int b = g >> 10;
    int k = g & (NK - 1);
    int row = (k == 0) ? y[b] : idx[g];
    out[g] = expf(S[(size_t)row * NB + b] * T_INV) * Z_INV;
}

// ------------------------------------------------- fallback full copy
__global__ void k_copy(const float* __restrict__ mem, float* __restrict__ temp) {
    size_t i = (size_t)blockIdx.x * 256 + threadIdx.x;
    ((float4*)temp)[i] = ((const float4*)mem)[i];
}

// ---------------------- 4) temp[y[b]] = normalize(MOM*mem[y[b]] + (1-MOM)*feat[b])
__global__ void k_scatter(const float* __restrict__ mem, const float* __restrict__ feat,
                          const int* __restrict__ y, float* __restrict__ temp) {
    __shared__ float sh[4];
    int b  = blockIdx.x;
    int yb = y[b];
    for (int b2 = b + 1; b2 < NB; ++b2)
        if (y[b2] == yb) return;                 // last-write-wins, uniform branch
    int t = threadIdx.x;
    const float4* f4 = (const float4*)(feat + (size_t)b * ND);
    const float4* m4 = (const float4*)(mem  + (size_t)yb * ND);
    float4 f0 = f4[t], f1 = f4[t + 256];
    float4 m0 = m4[t], m1 = m4[t + 256];
    float4 w0 = make_float4(m0.x*MOM + f0.x*(1.f-MOM), m0.y*MOM + f0.y*(1.f-MOM),
                            m0.z*MOM + f0.z*(1.f-MOM), m0.w*MOM + f0.w*(1.f-MOM));
    float4 w1 = make_float4(m1.x*MOM + f1.x*(1.f-MOM), m1.y*MOM + f1.y*(1.f-MOM),
                            m1.z*MOM + f1.z*(1.f-MOM), m1.w*MOM + f1.w*(1.f-MOM));
    float ss = w0.x*w0.x + w0.y*w0.y + w0.z*w0.z + w0.w*w0.w
             + w1.x*w1.x + w1.y*w1.y + w1.z*w1.z + w1.w*w1.w;
    float s = blk_reduce_sum256(ss, sh);
    float r = rsqrtf(s);
    float4* d = (float4*)(temp + (size_t)yb * ND);
    d[t]       = make_float4(w0.x*r, w0.y*r, w0.z*r, w0.w*r);
    d[t + 256] = make_float4(w1.x*r, w1.y*r, w1.z*r, w1.w*r);
}

// ---------------------------------------------------------------- launch
extern "C" void kernel_launch(void* const* d_in, const int* in_sizes, int n_in,
                              void* d_out, int out_size, void* d_ws, size_t ws_size,
                              hipStream_t stream) {
    (void)in_sizes; (void)n_in; (void)out_size;
    const float* x   = (const float*)d_in[0];
    const int*   y   = (const int*)d_in[1];
    const int*   idx = (const int*)d_in[2];
    const float* mem = (const float*)d_in[3];

    float* out  = (float*)d_out;                       // [B*K]
    float* temp = (float*)d_out + (size_t)NB * NK;     // [N*D]

    const size_t szF  = (size_t)NB * ND * sizeof(float);    // 2 MB  feat fp32
    const size_t szFB = (size_t)NB * ND * sizeof(short);    // 1 MB  feat bf16
    const size_t szS  = (size_t)NN * NB * sizeof(float);    // 51.2 MB scores
    const int gemm_grid = (NN + BMW - 1) / BMW;             // 1563

    if (ws_size >= szF + szFB + szS) {
        float*        feat  = (float*)d_ws;
        unsigned int* featb = (unsigned int*)((char*)d_ws + szF);
        float*        Smat  = (float*)((char*)d_ws + szF + szFB);
        k_feat<<<NB, 256, 0, stream>>>(x, feat, featb);
        k_gemm<true><<<gemm_grid, 64, 0, stream>>>(mem, (const short*)featb, Smat, temp);
        k_out<<<(NB * NK) / 256, 256, 0, stream>>>(Smat, idx, y, out);
        k_scatter<<<NB, 256, 0, stream>>>(mem, feat, y, temp);
    } else {
        float*        feat  = (float*)d_ws;
        unsigned int* featb = (unsigned int*)temp;
        float*        Smat  = (float*)((char*)temp + szFB);
        k_feat<<<NB, 256, 0, stream>>>(x, feat, featb);
        k_gemm<false><<<gemm_grid, 64, 0, stream>>>(mem, (const short*)featb, Smat, nullptr);
        k_out<<<(NB * NK) / 256, 256, 0, stream>>>(Smat, idx, y, out);
        k_copy<<<(NN * ND / 4) / 256, 256, 0, stream>>>(mem, temp);
        k_scatter<<<NB, 256, 0, stream>>>(mem, feat, y, temp);
    }
}